// Round 1
// baseline (357.961 us; speedup 1.0000x reference)
//
#include <hip/hip_runtime.h>
#include <hip/hip_bf16.h>
#include <stdint.h>

#define SEQ    2048
#define HDIM   64
#define NHEAD  16
#define NBATCH 2
#define HID    1024
#define MAXP   2048

typedef __attribute__((ext_vector_type(8))) short bf16x8;
typedef __attribute__((ext_vector_type(4))) float f32x4;

#define MFMA16(a,b,c) __builtin_amdgcn_mfma_f32_16x16x32_bf16((a),(b),(c),0,0,0)

static __device__ __forceinline__ unsigned short f2bf(float x){
  union { __hip_bfloat16 h; unsigned short u; } c; c.h = __float2bfloat16(x); return c.u;
}
static __device__ __forceinline__ float bf2f(unsigned short u){
  union { __hip_bfloat16 h; unsigned short u; } c; c.u = u; return __bfloat162float(c.h);
}

// ---------------- f32 -> bf16 convert ----------------
__global__ void cvt_kernel(const float* __restrict__ src, unsigned short* __restrict__ dst, int n4){
  int i = blockIdx.x*blockDim.x + threadIdx.x;
  int stride = gridDim.x*blockDim.x;
  for (int idx = i; idx < n4; idx += stride){
    float4 v = reinterpret_cast<const float4*>(src)[idx];
    ushort4 o;
    o.x = f2bf(v.x); o.y = f2bf(v.y); o.z = f2bf(v.z); o.w = f2bf(v.w);
    reinterpret_cast<ushort4*>(dst)[idx] = o;
  }
}

// ---------------- QKV projection GEMM ----------------
// C[m,n] = sum_k X[m,k] * W[n,k] + bias[n];  m = b*SEQ+s, n = h*64+d
// writes bf16 to [B,H,S,D]
__global__ __launch_bounds__(256,2) void qkv_gemm(
    const unsigned short* __restrict__ X,
    const unsigned short* __restrict__ Wq_, const unsigned short* __restrict__ Wk_,
    const unsigned short* __restrict__ Wv_,
    const float* __restrict__ bq_, const float* __restrict__ bk_, const float* __restrict__ bv_,
    unsigned short* __restrict__ Qb, unsigned short* __restrict__ Kb, unsigned short* __restrict__ Vb)
{
  __shared__ __align__(16) unsigned short Al[128*72];
  __shared__ __align__(16) unsigned short Bl[128*72];
  const int tid = threadIdx.x;
  const int ln = tid & 63, wv = tid >> 6;
  const int l15 = ln & 15, g = ln >> 4;
  const int wr = wv >> 1, wc = wv & 1;

  const int bn = blockIdx.x, bm = blockIdx.y, mat = blockIdx.z;
  const unsigned short* W = (mat==0) ? Wq_ : ((mat==1) ? Wk_ : Wv_);
  const float* bias = (mat==0) ? bq_ : ((mat==1) ? bk_ : bv_);
  unsigned short* Out = (mat==0) ? Qb : ((mat==1) ? Kb : Vb);

  const int m0 = bm*128, n0 = bn*128;

  f32x4 acc[4][4];
  #pragma unroll
  for (int i=0;i<4;++i)
    #pragma unroll
    for (int j=0;j<4;++j) acc[i][j] = (f32x4){0.f,0.f,0.f,0.f};

  for (int kk = 0; kk < HID; kk += 64){
    #pragma unroll
    for (int p=0;p<4;++p){
      int lin = tid + 256*p;
      int row = lin >> 3, ch = lin & 7;
      *reinterpret_cast<bf16x8*>(&Al[row*72 + ch*8]) =
        *reinterpret_cast<const bf16x8*>(&X[(size_t)(m0+row)*HID + kk + ch*8]);
      *reinterpret_cast<bf16x8*>(&Bl[row*72 + ch*8]) =
        *reinterpret_cast<const bf16x8*>(&W[(size_t)(n0+row)*HID + kk + ch*8]);
    }
    __syncthreads();
    bf16x8 a0[4], a1[4], b0[4], b1[4];
    #pragma unroll
    for (int mi=0;mi<4;++mi){
      const unsigned short* p = &Al[(64*wr + 16*mi + l15)*72 + g*8];
      a0[mi] = *reinterpret_cast<const bf16x8*>(p);
      a1[mi] = *reinterpret_cast<const bf16x8*>(p + 32);
    }
    #pragma unroll
    for (int ni=0;ni<4;++ni){
      const unsigned short* p = &Bl[(64*wc + 16*ni + l15)*72 + g*8];
      b0[ni] = *reinterpret_cast<const bf16x8*>(p);
      b1[ni] = *reinterpret_cast<const bf16x8*>(p + 32);
    }
    #pragma unroll
    for (int mi=0;mi<4;++mi)
      #pragma unroll
      for (int ni=0;ni<4;++ni){
        acc[mi][ni] = MFMA16(a0[mi], b0[ni], acc[mi][ni]);
        acc[mi][ni] = MFMA16(a1[mi], b1[ni], acc[mi][ni]);
      }
    __syncthreads();
  }
  #pragma unroll
  for (int mi=0;mi<4;++mi)
    #pragma unroll
    for (int ni=0;ni<4;++ni)
      #pragma unroll
      for (int r=0;r<4;++r){
        int m = m0 + 64*wr + 16*mi + 4*g + r;
        int n = n0 + 64*wc + 16*ni + l15;
        float v = acc[mi][ni][r] + bias[n];
        int b = m >> 11, s = m & 2047;
        int h = n >> 6, d = n & 63;
        Out[(((size_t)(b*NHEAD + h))*SEQ + s)*HDIM + d] = f2bf(v);
      }
}

// ---------------- V transpose: [B,H,S,D] -> [B,H,D,S] ----------------
__global__ void vtrans(const unsigned short* __restrict__ Vb, unsigned short* __restrict__ VTb){
  __shared__ __align__(16) unsigned short Vl[64*72];
  const int tid = threadIdx.x;
  const int blk = blockIdx.x;
  const int st = blk & 31, bh = blk >> 5;
  const int s0 = st*64;
  const unsigned short* src = Vb + (size_t)bh*SEQ*HDIM;
  unsigned short* dst = VTb + (size_t)bh*HDIM*SEQ;
  #pragma unroll
  for (int p=0;p<2;++p){
    int lin = tid + 256*p;
    int row = lin >> 3, ch = lin & 7;
    *reinterpret_cast<bf16x8*>(&Vl[row*72 + ch*8]) =
      *reinterpret_cast<const bf16x8*>(&src[(size_t)(s0+row)*HDIM + ch*8]);
  }
  __syncthreads();
  #pragma unroll
  for (int p=0;p<2;++p){
    int lin = tid + 256*p;
    int drow = lin >> 3, sch = lin & 7;
    bf16x8 v;
    #pragma unroll
    for (int j=0;j<8;++j) v[j] = (short)Vl[(sch*8+j)*72 + drow];
    *reinterpret_cast<bf16x8*>(&dst[(size_t)drow*SEQ + s0 + sch*8]) = v;
  }
}

// ---------------- fused attention with relative position bias ----------------
// per block: one (b,h) and 64 q rows. 4 waves, each 16 q rows.
#define KP 72    // padded row stride (elems) for K/V/E/P tiles
#define GP 132   // row stride for G1/G2 (scalar bf16 access)

__global__ __launch_bounds__(256,2) void attn_kernel(
    const unsigned short* __restrict__ Qb,
    const unsigned short* __restrict__ Kb,
    const unsigned short* __restrict__ VTb,
    const unsigned short* __restrict__ Eb,
    float* __restrict__ out)
{
  __shared__ __align__(16) unsigned short K_l[64*KP];
  __shared__ __align__(16) unsigned short V_l[64*KP];   // V^T tile: [d][k]
  __shared__ __align__(16) unsigned short E_l[128*KP];
  __shared__ __align__(16) unsigned short G2_l[64*GP];
  __shared__ __align__(16) unsigned short G1_l[4][16*GP];
  __shared__ __align__(16) unsigned short P_l[4][16*KP];

  const int tid = threadIdx.x;
  const int ln = tid & 63, wv = tid >> 6;
  const int l15 = ln & 15, g = ln >> 4;

  const int blk = blockIdx.x;
  const int qt = blk & 31, bh = blk >> 5;
  const int q0 = qt*64;

  const unsigned short* Qg = Qb + (size_t)bh*SEQ*HDIM;
  const unsigned short* Kg = Kb + (size_t)bh*SEQ*HDIM;
  const unsigned short* Vg = VTb + (size_t)bh*HDIM*SEQ;

  // Q fragments: wave wv owns q rows [q0+16wv, q0+16wv+16)
  bf16x8 qa0, qa1;
  {
    const unsigned short* p = &Qg[(size_t)(q0 + 16*wv + l15)*HDIM + g*8];
    qa0 = *reinterpret_cast<const bf16x8*>(p);
    qa1 = *reinterpret_cast<const bf16x8*>(p + 32);
  }

  f32x4 oacc[4];
  #pragma unroll
  for (int i=0;i<4;++i) oacc[i] = (f32x4){0.f,0.f,0.f,0.f};
  float mrow[4] = {-1e30f,-1e30f,-1e30f,-1e30f};
  float lrow[4] = {0.f,0.f,0.f,0.f};

  for (int kt = 0; kt < SEQ/64; ++kt){
    const int k0 = kt*64;
    const int idx_min = MAXP - 1 + q0 - k0 - 63;   // in [0, 3968]

    // ---- stage K (64x64), VT (64x64), E-band (127x64) ----
    #pragma unroll
    for (int p=0;p<2;++p){
      int lin = tid + 256*p; int row = lin>>3, ch = lin&7;
      *reinterpret_cast<bf16x8*>(&K_l[row*KP + ch*8]) =
        *reinterpret_cast<const bf16x8*>(&Kg[(size_t)(k0+row)*HDIM + ch*8]);
    }
    #pragma unroll
    for (int p=0;p<2;++p){
      int lin = tid + 256*p; int row = lin>>3, ch = lin&7;
      *reinterpret_cast<bf16x8*>(&V_l[row*KP + ch*8]) =
        *reinterpret_cast<const bf16x8*>(&Vg[(size_t)row*SEQ + k0 + ch*8]);
    }
    #pragma unroll
    for (int p=0;p<4;++p){
      int lin = tid + 256*p; int row = lin>>3, ch = lin&7;
      bf16x8 v = {0,0,0,0,0,0,0,0};
      if (row < 127)
        v = *reinterpret_cast<const bf16x8*>(&Eb[(size_t)(idx_min+row)*HDIM + ch*8]);
      *reinterpret_cast<bf16x8*>(&E_l[row*KP + ch*8]) = v;
    }
    __syncthreads();

    // ---- G2[k,t] = K·E^T (shared, wave computes its 16-k band) and
    //      G1[q,t] = Q·E^T (per-wave) ----
    bf16x8 ka0, ka1;
    {
      const unsigned short* p = &K_l[(16*wv + l15)*KP + g*8];
      ka0 = *reinterpret_cast<const bf16x8*>(p);
      ka1 = *reinterpret_cast<const bf16x8*>(p + 32);
    }
    #pragma unroll
    for (int ct=0; ct<8; ++ct){
      const unsigned short* p = &E_l[(16*ct + l15)*KP + g*8];
      bf16x8 eb0 = *reinterpret_cast<const bf16x8*>(p);
      bf16x8 eb1 = *reinterpret_cast<const bf16x8*>(p + 32);
      f32x4 g2a = (f32x4){0.f,0.f,0.f,0.f};
      g2a = MFMA16(ka0, eb0, g2a);
      g2a = MFMA16(ka1, eb1, g2a);
      f32x4 g1a = (f32x4){0.f,0.f,0.f,0.f};
      g1a = MFMA16(qa0, eb0, g1a);
      g1a = MFMA16(qa1, eb1, g1a);
      #pragma unroll
      for (int r=0;r<4;++r){
        G2_l[(16*wv + 4*g + r)*GP + 16*ct + l15] = f2bf(g2a[r]);
        G1_l[wv][(4*g + r)*GP + 16*ct + l15]     = f2bf(g1a[r]);
      }
    }

    // ---- S1 = Q·K^T ----
    f32x4 sacc[4];
    #pragma unroll
    for (int ct=0; ct<4; ++ct){
      const unsigned short* p = &K_l[(16*ct + l15)*KP + g*8];
      bf16x8 kb0 = *reinterpret_cast<const bf16x8*>(p);
      bf16x8 kb1 = *reinterpret_cast<const bf16x8*>(p + 32);
      f32x4 a = (f32x4){0.f,0.f,0.f,0.f};
      a = MFMA16(qa0, kb0, a);
      a = MFMA16(qa1, kb1, a);
      sacc[ct] = a;
    }
    __syncthreads();   // G2 visible to all waves

    // ---- gather rel-pos terms + online softmax ----
    float sc[4][4];
    #pragma unroll
    for (int ct=0; ct<4; ++ct)
      #pragma unroll
      for (int r=0;r<4;++r){
        int qloc = 4*g + r;            // wave-local q row 0..15
        int kk2  = 16*ct + l15;        // k col 0..63
        int t    = 16*wv + qloc - kk2 + 63;   // 0..126
        sc[ct][r] = sacc[ct][r]*0.125f
                  + bf2f(G1_l[wv][qloc*GP + t])
                  + bf2f(G2_l[kk2*GP + t]);
      }
    #pragma unroll
    for (int r=0;r<4;++r){
      float m = fmaxf(fmaxf(sc[0][r], sc[1][r]), fmaxf(sc[2][r], sc[3][r]));
      #pragma unroll
      for (int off=1; off<16; off<<=1) m = fmaxf(m, __shfl_xor(m, off, 64));
      float mn = fmaxf(m, mrow[r]);
      float corr = __expf(mrow[r] - mn);
      float s = 0.f;
      #pragma unroll
      for (int ct=0;ct<4;++ct){ float pv = __expf(sc[ct][r] - mn); sc[ct][r] = pv; s += pv; }
      #pragma unroll
      for (int off=1; off<16; off<<=1) s += __shfl_xor(s, off, 64);
      lrow[r] = lrow[r]*corr + s;
      mrow[r] = mn;
      #pragma unroll
      for (int ctd=0;ctd<4;++ctd) oacc[ctd][r] *= corr;
    }
    // write P (per-wave)
    #pragma unroll
    for (int ct=0;ct<4;++ct)
      #pragma unroll
      for (int r=0;r<4;++r)
        P_l[wv][(4*g + r)*KP + 16*ct + l15] = f2bf(sc[ct][r]);

    // ---- PV: O += P·V ----
    bf16x8 pa0, pa1;
    {
      const unsigned short* p = &P_l[wv][l15*KP + g*8];
      pa0 = *reinterpret_cast<const bf16x8*>(p);
      pa1 = *reinterpret_cast<const bf16x8*>(p + 32);
    }
    #pragma unroll
    for (int ctd=0; ctd<4; ++ctd){
      const unsigned short* p = &V_l[(16*ctd + l15)*KP + g*8];
      bf16x8 vb0 = *reinterpret_cast<const bf16x8*>(p);
      bf16x8 vb1 = *reinterpret_cast<const bf16x8*>(p + 32);
      oacc[ctd] = MFMA16(pa0, vb0, oacc[ctd]);
      oacc[ctd] = MFMA16(pa1, vb1, oacc[ctd]);
    }
    __syncthreads();   // all reads done before next stage overwrites
  }

  const int b = bh >> 4, h = bh & 15;
  #pragma unroll
  for (int ctd=0; ctd<4; ++ctd)
    #pragma unroll
    for (int r=0;r<4;++r){
      int row = q0 + 16*wv + 4*g + r;
      int d = 16*ctd + l15;
      out[((size_t)(b*SEQ + row))*HID + h*HDIM + d] = oacc[ctd][r] / lrow[r];
    }
}

// ---------------- launch ----------------
extern "C" void kernel_launch(void* const* d_in, const int* in_sizes, int n_in,
                              void* d_out, int out_size, void* d_ws, size_t ws_size,
                              hipStream_t stream){
  const float* hs = (const float*)d_in[0];
  const float* Wq = (const float*)d_in[1];
  const float* bq = (const float*)d_in[2];
  const float* Wk = (const float*)d_in[3];
  const float* bk = (const float*)d_in[4];
  const float* Wv = (const float*)d_in[5];
  const float* bv = (const float*)d_in[6];
  const float* de = (const float*)d_in[7];
  float* out = (float*)d_out;

  char* ws = (char*)d_ws;
  unsigned short* Xb  = (unsigned short*)(ws);                       // 8,388,608 B
  unsigned short* Wqb = (unsigned short*)(ws + 8388608);             // 2 MB
  unsigned short* Wkb = (unsigned short*)(ws + 8388608 + 2097152);
  unsigned short* Wvb = (unsigned short*)(ws + 8388608 + 2*2097152);
  unsigned short* Eb  = (unsigned short*)(ws + 14680064);            // 524,160 B
  unsigned short* Qb  = (unsigned short*)(ws + 15204352);
  unsigned short* Kb  = (unsigned short*)(ws + 23592960);
  unsigned short* Vb  = (unsigned short*)(ws + 31981568);
  unsigned short* VTb = (unsigned short*)(ws + 40370176);            // end 48,758,784

  cvt_kernel<<<1024,256,0,stream>>>(hs, Xb, 4194304/4);
  cvt_kernel<<<512,256,0,stream>>>(Wq, Wqb, 1048576/4);
  cvt_kernel<<<512,256,0,stream>>>(Wk, Wkb, 1048576/4);
  cvt_kernel<<<512,256,0,stream>>>(Wv, Wvb, 1048576/4);
  cvt_kernel<<<256,256,0,stream>>>(de, Eb, 262080/4);

  dim3 gg(8,32,3);
  qkv_gemm<<<gg,256,0,stream>>>(Xb, Wqb, Wkb, Wvb, bq, bk, bv, Qb, Kb, Vb);
  vtrans<<<1024,256,0,stream>>>(Vb, VTb);
  attn_kernel<<<1024,256,0,stream>>>(Qb, Kb, VTb, Eb, out);
}

// Round 2
// 277.299 us; speedup vs baseline: 1.2909x; 1.2909x over previous
//
#include <hip/hip_runtime.h>
#include <hip/hip_bf16.h>
#include <stdint.h>

#define SEQ    2048
#define HDIM   64
#define NHEAD  16
#define NBATCH 2
#define HID    1024
#define MAXP   2048

typedef __attribute__((ext_vector_type(8))) short bf16x8;
typedef __attribute__((ext_vector_type(4))) float f32x4;

#define MFMA16(a,b,c) __builtin_amdgcn_mfma_f32_16x16x32_bf16((a),(b),(c),0,0,0)

static __device__ __forceinline__ unsigned short f2bf(float x){
  union { __hip_bfloat16 h; unsigned short u; } c; c.h = __float2bfloat16(x); return c.u;
}
static __device__ __forceinline__ float bf2f(unsigned short u){
  union { __hip_bfloat16 h; unsigned short u; } c; c.u = u; return __bfloat162float(c.h);
}

// ---------------- f32 -> bf16 convert ----------------
__global__ void cvt_kernel(const float* __restrict__ src, unsigned short* __restrict__ dst, int n4){
  int i = blockIdx.x*blockDim.x + threadIdx.x;
  int stride = gridDim.x*blockDim.x;
  for (int idx = i; idx < n4; idx += stride){
    float4 v = reinterpret_cast<const float4*>(src)[idx];
    ushort4 o;
    o.x = f2bf(v.x); o.y = f2bf(v.y); o.z = f2bf(v.z); o.w = f2bf(v.w);
    reinterpret_cast<ushort4*>(dst)[idx] = o;
  }
}

// ---------------- QKV projection GEMM ----------------
__global__ __launch_bounds__(256,2) void qkv_gemm(
    const unsigned short* __restrict__ X,
    const unsigned short* __restrict__ Wq_, const unsigned short* __restrict__ Wk_,
    const unsigned short* __restrict__ Wv_,
    const float* __restrict__ bq_, const float* __restrict__ bk_, const float* __restrict__ bv_,
    unsigned short* __restrict__ Qb, unsigned short* __restrict__ Kb, unsigned short* __restrict__ Vb)
{
  __shared__ __align__(16) unsigned short Al[128*72];
  __shared__ __align__(16) unsigned short Bl[128*72];
  const int tid = threadIdx.x;
  const int ln = tid & 63, wv = tid >> 6;
  const int l15 = ln & 15, g = ln >> 4;
  const int wr = wv >> 1, wc = wv & 1;

  const int bn = blockIdx.x, bm = blockIdx.y, mat = blockIdx.z;
  const unsigned short* W = (mat==0) ? Wq_ : ((mat==1) ? Wk_ : Wv_);
  const float* bias = (mat==0) ? bq_ : ((mat==1) ? bk_ : bv_);
  unsigned short* Out = (mat==0) ? Qb : ((mat==1) ? Kb : Vb);

  const int m0 = bm*128, n0 = bn*128;

  f32x4 acc[4][4];
  #pragma unroll
  for (int i=0;i<4;++i)
    #pragma unroll
    for (int j=0;j<4;++j) acc[i][j] = (f32x4){0.f,0.f,0.f,0.f};

  for (int kk = 0; kk < HID; kk += 64){
    #pragma unroll
    for (int p=0;p<4;++p){
      int lin = tid + 256*p;
      int row = lin >> 3, ch = lin & 7;
      *reinterpret_cast<bf16x8*>(&Al[row*72 + ch*8]) =
        *reinterpret_cast<const bf16x8*>(&X[(size_t)(m0+row)*HID + kk + ch*8]);
      *reinterpret_cast<bf16x8*>(&Bl[row*72 + ch*8]) =
        *reinterpret_cast<const bf16x8*>(&W[(size_t)(n0+row)*HID + kk + ch*8]);
    }
    __syncthreads();
    bf16x8 a0[4], a1[4], b0[4], b1[4];
    #pragma unroll
    for (int mi=0;mi<4;++mi){
      const unsigned short* p = &Al[(64*wr + 16*mi + l15)*72 + g*8];
      a0[mi] = *reinterpret_cast<const bf16x8*>(p);
      a1[mi] = *reinterpret_cast<const bf16x8*>(p + 32);
    }
    #pragma unroll
    for (int ni=0;ni<4;++ni){
      const unsigned short* p = &Bl[(64*wc + 16*ni + l15)*72 + g*8];
      b0[ni] = *reinterpret_cast<const bf16x8*>(p);
      b1[ni] = *reinterpret_cast<const bf16x8*>(p + 32);
    }
    #pragma unroll
    for (int mi=0;mi<4;++mi)
      #pragma unroll
      for (int ni=0;ni<4;++ni){
        acc[mi][ni] = MFMA16(a0[mi], b0[ni], acc[mi][ni]);
        acc[mi][ni] = MFMA16(a1[mi], b1[ni], acc[mi][ni]);
      }
    __syncthreads();
  }
  #pragma unroll
  for (int mi=0;mi<4;++mi)
    #pragma unroll
    for (int ni=0;ni<4;++ni)
      #pragma unroll
      for (int r=0;r<4;++r){
        int m = m0 + 64*wr + 16*mi + 4*g + r;
        int n = n0 + 64*wc + 16*ni + l15;
        float v = acc[mi][ni][r] + bias[n];
        int b = m >> 11, s = m & 2047;
        int h = n >> 6, d = n & 63;
        Out[(((size_t)(b*NHEAD + h))*SEQ + s)*HDIM + d] = f2bf(v);
      }
}

// ---------------- V transpose: [B,H,S,D] -> [B,H,D,S] ----------------
__global__ void vtrans(const unsigned short* __restrict__ Vb, unsigned short* __restrict__ VTb){
  __shared__ __align__(16) unsigned short Vl[64*72];
  const int tid = threadIdx.x;
  const int blk = blockIdx.x;
  const int st = blk & 31, bh = blk >> 5;
  const int s0 = st*64;
  const unsigned short* src = Vb + (size_t)bh*SEQ*HDIM;
  unsigned short* dst = VTb + (size_t)bh*HDIM*SEQ;
  #pragma unroll
  for (int p=0;p<2;++p){
    int lin = tid + 256*p;
    int row = lin >> 3, ch = lin & 7;
    *reinterpret_cast<bf16x8*>(&Vl[row*72 + ch*8]) =
      *reinterpret_cast<const bf16x8*>(&src[(size_t)(s0+row)*HDIM + ch*8]);
  }
  __syncthreads();
  #pragma unroll
  for (int p=0;p<2;++p){
    int lin = tid + 256*p;
    int drow = lin >> 3, sch = lin & 7;
    bf16x8 v;
    #pragma unroll
    for (int j=0;j<8;++j) v[j] = (short)Vl[(sch*8+j)*72 + drow];
    *reinterpret_cast<bf16x8*>(&dst[(size_t)drow*SEQ + s0 + sch*8]) = v;
  }
}

// ---------------- fused attention with relative position bias ----------------
// Diagonal re-layout:
//   t = qhat - khat + 63 (qhat,khat block-local in [0,63])
//   G1 (Q·E): stored wave-private  G1D[wv][u][qloc], u = t - qhat = 63 - khat  (bf16)
//   G2 (K·E): stored shared        G2S[khat][qhat] = G2[khat][qhat-khat+63]    (f32)
// Consumer reads are then contiguous 4-vectors (b64 / b128) per score fragment.
#define KP  72    // padded row stride (elems) for K/V/E/P tiles
#define G2P 68    // f32 row stride for G2S (16B aligned, 2-way banks)
#define G1P 20    // bf16 row stride for G1D (8B aligned rows, conflict-free)

__global__ __launch_bounds__(256,2) void attn_kernel(
    const unsigned short* __restrict__ Qb,
    const unsigned short* __restrict__ Kb,
    const unsigned short* __restrict__ VTb,
    const unsigned short* __restrict__ Eb,
    float* __restrict__ out)
{
  __shared__ __align__(16) unsigned short K_l[64*KP];
  __shared__ __align__(16) unsigned short V_l[64*KP];   // V^T tile: [d][k]
  __shared__ __align__(16) unsigned short E_l[128*KP];
  __shared__ __align__(16) float          G2S[64*G2P];
  __shared__ __align__(16) unsigned short G1D[4][64*G1P];
  __shared__ __align__(16) unsigned short P_l[4][16*KP];

  const int tid = threadIdx.x;
  const int ln = tid & 63, wv = tid >> 6;
  const int l15 = ln & 15, g = ln >> 4;
  const int qloc0 = 4*g;
  const int srow = tid >> 3, sch = tid & 7;   // staging: row srow+32p, 16B chunk sch

  const int blk = blockIdx.x;
  const int qt = blk & 31, bh = blk >> 5;
  const int q0 = qt*64;

  const unsigned short* Qg = Qb + (size_t)bh*SEQ*HDIM;
  const unsigned short* Kg = Kb + (size_t)bh*SEQ*HDIM;
  const unsigned short* Vg = VTb + (size_t)bh*HDIM*SEQ;

  // Q fragments: wave wv owns q rows [q0+16wv, q0+16wv+16)
  bf16x8 qa0, qa1;
  {
    const unsigned short* p = &Qg[(size_t)(q0 + 16*wv + l15)*HDIM + g*8];
    qa0 = *reinterpret_cast<const bf16x8*>(p);
    qa1 = *reinterpret_cast<const bf16x8*>(p + 32);
  }

  f32x4 oacc[4];
  #pragma unroll
  for (int i=0;i<4;++i) oacc[i] = (f32x4){0.f,0.f,0.f,0.f};
  float mrow[4] = {-1e30f,-1e30f,-1e30f,-1e30f};
  float lrow[4] = {0.f,0.f,0.f,0.f};

  // register prefetch of staging tile kt=0
  bf16x8 stK[2], stV[2], stE[4];
  {
    const int idx_min = 1984 + q0;
    #pragma unroll
    for (int p=0;p<2;++p){
      int row = srow + 32*p;
      stK[p] = *reinterpret_cast<const bf16x8*>(&Kg[(size_t)row*HDIM + sch*8]);
      stV[p] = *reinterpret_cast<const bf16x8*>(&Vg[(size_t)row*SEQ + sch*8]);
    }
    #pragma unroll
    for (int p=0;p<4;++p){
      int row = srow + 32*p;
      bf16x8 z = {0,0,0,0,0,0,0,0};
      stE[p] = (row < 127)
        ? *reinterpret_cast<const bf16x8*>(&Eb[(size_t)(idx_min+row)*HDIM + sch*8]) : z;
    }
  }

  for (int kt = 0; kt < SEQ/64; ++kt){
    // ---- write staged regs -> LDS (reads of previous tile all completed before
    //      barrier B of the previous iteration) ----
    #pragma unroll
    for (int p=0;p<2;++p){
      int row = srow + 32*p;
      *reinterpret_cast<bf16x8*>(&K_l[row*KP + sch*8]) = stK[p];
      *reinterpret_cast<bf16x8*>(&V_l[row*KP + sch*8]) = stV[p];
    }
    #pragma unroll
    for (int p=0;p<4;++p){
      int row = srow + 32*p;
      *reinterpret_cast<bf16x8*>(&E_l[row*KP + sch*8]) = stE[p];
    }
    // ---- issue next tile's global loads (latency hidden under compute) ----
    if (kt < SEQ/64 - 1){
      const int k0n = (kt+1)*64;
      const int idx_minn = 1984 + q0 - k0n;
      #pragma unroll
      for (int p=0;p<2;++p){
        int row = srow + 32*p;
        stK[p] = *reinterpret_cast<const bf16x8*>(&Kg[(size_t)(k0n+row)*HDIM + sch*8]);
        stV[p] = *reinterpret_cast<const bf16x8*>(&Vg[(size_t)row*SEQ + k0n + sch*8]);
      }
      #pragma unroll
      for (int p=0;p<4;++p){
        int row = srow + 32*p;
        bf16x8 z = {0,0,0,0,0,0,0,0};
        stE[p] = (row < 127)
          ? *reinterpret_cast<const bf16x8*>(&Eb[(size_t)(idx_minn+row)*HDIM + sch*8]) : z;
      }
    }
    __syncthreads();   // A: staging visible

    // ---- V fragments -> registers (so V_l reads finish before barrier B) ----
    bf16x8 vb0[4], vb1[4];
    #pragma unroll
    for (int ctd=0; ctd<4; ++ctd){
      const unsigned short* p = &V_l[(16*ctd + l15)*KP + g*8];
      vb0[ctd] = *reinterpret_cast<const bf16x8*>(p);
      vb1[ctd] = *reinterpret_cast<const bf16x8*>(p + 32);
    }
    bf16x8 ka0, ka1;
    {
      const unsigned short* p = &K_l[(16*wv + l15)*KP + g*8];
      ka0 = *reinterpret_cast<const bf16x8*>(p);
      ka1 = *reinterpret_cast<const bf16x8*>(p + 32);
    }

    __builtin_amdgcn_s_setprio(1);
    // ---- G2 production: wave wv covers khat in [16wv,16wv+16), t-tiles 3-wv..7-wv ----
    #pragma unroll
    for (int j=0;j<5;++j){
      int trow = 16*(3 - wv + j) + l15;
      const unsigned short* p = &E_l[trow*KP + g*8];
      bf16x8 eb0 = *reinterpret_cast<const bf16x8*>(p);
      bf16x8 eb1 = *reinterpret_cast<const bf16x8*>(p + 32);
      f32x4 a = (f32x4){0.f,0.f,0.f,0.f};
      a = MFMA16(ka0, eb0, a);
      a = MFMA16(ka1, eb1, a);
      #pragma unroll
      for (int r=0;r<4;++r){
        int qh = 16*j + l15 + qloc0 + r - 15;   // qhat
        if (qh >= 0 && qh <= 63)
          G2S[(16*wv + qloc0 + r)*G2P + qh] = a[r];
      }
    }
    // ---- G1 production: t-tiles wv..wv+4, wave-private store ----
    #pragma unroll
    for (int c=0;c<5;++c){
      int trow = 16*(wv + c) + l15;
      const unsigned short* p = &E_l[trow*KP + g*8];
      bf16x8 eb0 = *reinterpret_cast<const bf16x8*>(p);
      bf16x8 eb1 = *reinterpret_cast<const bf16x8*>(p + 32);
      f32x4 a = (f32x4){0.f,0.f,0.f,0.f};
      a = MFMA16(qa0, eb0, a);
      a = MFMA16(qa1, eb1, a);
      #pragma unroll
      for (int r=0;r<4;++r){
        int u = 16*c + l15 - (qloc0 + r);
        if (u >= 0 && u <= 63)
          G1D[wv][u*G1P + qloc0 + r] = f2bf(a[r]);
      }
    }
    // ---- S1 = Q·K^T ----
    f32x4 sacc[4];
    #pragma unroll
    for (int ct=0; ct<4; ++ct){
      const unsigned short* p = &K_l[(16*ct + l15)*KP + g*8];
      bf16x8 kb0 = *reinterpret_cast<const bf16x8*>(p);
      bf16x8 kb1 = *reinterpret_cast<const bf16x8*>(p + 32);
      f32x4 a = (f32x4){0.f,0.f,0.f,0.f};
      a = MFMA16(qa0, kb0, a);
      a = MFMA16(qa1, kb1, a);
      sacc[ct] = a;
    }
    __builtin_amdgcn_s_setprio(0);
    __syncthreads();   // B: G2S visible; all K/V/E reads complete

    // ---- vectorized gather + online softmax ----
    float sc[4][4];
    #pragma unroll
    for (int ct=0; ct<4; ++ct){
      int u = 63 - 16*ct - l15;
      ushort4 g1 = *reinterpret_cast<const ushort4*>(&G1D[wv][u*G1P + qloc0]);
      float4  g2 = *reinterpret_cast<const float4*>(&G2S[(16*ct + l15)*G2P + 16*wv + qloc0]);
      sc[ct][0] = sacc[ct][0]*0.125f + bf2f(g1.x) + g2.x;
      sc[ct][1] = sacc[ct][1]*0.125f + bf2f(g1.y) + g2.y;
      sc[ct][2] = sacc[ct][2]*0.125f + bf2f(g1.z) + g2.z;
      sc[ct][3] = sacc[ct][3]*0.125f + bf2f(g1.w) + g2.w;
    }
    #pragma unroll
    for (int r=0;r<4;++r){
      float m = fmaxf(fmaxf(sc[0][r], sc[1][r]), fmaxf(sc[2][r], sc[3][r]));
      #pragma unroll
      for (int off=1; off<16; off<<=1) m = fmaxf(m, __shfl_xor(m, off, 64));
      float mn = fmaxf(m, mrow[r]);
      float corr = __expf(mrow[r] - mn);
      float s = 0.f;
      #pragma unroll
      for (int ct=0;ct<4;++ct){ float pv = __expf(sc[ct][r] - mn); sc[ct][r] = pv; s += pv; }
      #pragma unroll
      for (int off=1; off<16; off<<=1) s += __shfl_xor(s, off, 64);
      lrow[r] = lrow[r]*corr + s;
      mrow[r] = mn;
      #pragma unroll
      for (int ctd=0;ctd<4;++ctd) oacc[ctd][r] *= corr;
    }
    // write P (per-wave private)
    #pragma unroll
    for (int ct=0;ct<4;++ct)
      #pragma unroll
      for (int r=0;r<4;++r)
        P_l[wv][(qloc0 + r)*KP + 16*ct + l15] = f2bf(sc[ct][r]);

    // ---- PV: O += P·V (V already in registers) ----
    bf16x8 pa0, pa1;
    {
      const unsigned short* p = &P_l[wv][l15*KP + g*8];
      pa0 = *reinterpret_cast<const bf16x8*>(p);
      pa1 = *reinterpret_cast<const bf16x8*>(p + 32);
    }
    __builtin_amdgcn_s_setprio(1);
    #pragma unroll
    for (int ctd=0; ctd<4; ++ctd){
      oacc[ctd] = MFMA16(pa0, vb0[ctd], oacc[ctd]);
      oacc[ctd] = MFMA16(pa1, vb1[ctd], oacc[ctd]);
    }
    __builtin_amdgcn_s_setprio(0);
    // no barrier: next loop's staging writes only touch K/V/E, whose reads all
    // precede barrier B; G1D/G2S/P are rewritten only after the next barrier A/B.
  }

  const int b = bh >> 4, h = bh & 15;
  #pragma unroll
  for (int ctd=0; ctd<4; ++ctd)
    #pragma unroll
    for (int r=0;r<4;++r){
      int row = q0 + 16*wv + qloc0 + r;
      int d = 16*ctd + l15;
      out[((size_t)(b*SEQ + row))*HID + h*HDIM + d] = oacc[ctd][r] / lrow[r];
    }
}

// ---------------- launch ----------------
extern "C" void kernel_launch(void* const* d_in, const int* in_sizes, int n_in,
                              void* d_out, int out_size, void* d_ws, size_t ws_size,
                              hipStream_t stream){
  const float* hs = (const float*)d_in[0];
  const float* Wq = (const float*)d_in[1];
  const float* bq = (const float*)d_in[2];
  const float* Wk = (const float*)d_in[3];
  const float* bk = (const float*)d_in[4];
  const float* Wv = (const float*)d_in[5];
  const float* bv = (const float*)d_in[6];
  const float* de = (const float*)d_in[7];
  float* out = (float*)d_out;

  char* ws = (char*)d_ws;
  unsigned short* Xb  = (unsigned short*)(ws);                       // 8,388,608 B
  unsigned short* Wqb = (unsigned short*)(ws + 8388608);             // 2 MB
  unsigned short* Wkb = (unsigned short*)(ws + 8388608 + 2097152);
  unsigned short* Wvb = (unsigned short*)(ws + 8388608 + 2*2097152);
  unsigned short* Eb  = (unsigned short*)(ws + 14680064);            // 524,160 B
  unsigned short* Qb  = (unsigned short*)(ws + 15204352);
  unsigned short* Kb  = (unsigned short*)(ws + 23592960);
  unsigned short* Vb  = (unsigned short*)(ws + 31981568);
  unsigned short* VTb = (unsigned short*)(ws + 40370176);            // end 48,758,784

  cvt_kernel<<<1024,256,0,stream>>>(hs, Xb, 4194304/4);
  cvt_kernel<<<512,256,0,stream>>>(Wq, Wqb, 1048576/4);
  cvt_kernel<<<512,256,0,stream>>>(Wk, Wkb, 1048576/4);
  cvt_kernel<<<512,256,0,stream>>>(Wv, Wvb, 1048576/4);
  cvt_kernel<<<256,256,0,stream>>>(de, Eb, 262080/4);

  dim3 gg(8,32,3);
  qkv_gemm<<<gg,256,0,stream>>>(Xb, Wqb, Wkb, Wvb, bq, bk, bv, Qb, Kb, Vb);
  vtrans<<<1024,256,0,stream>>>(Vb, VTb);
  attn_kernel<<<1024,256,0,stream>>>(Qb, Kb, VTb, Eb, out);
}

// Round 3
// 218.758 us; speedup vs baseline: 1.6363x; 1.2676x over previous
//
#include <hip/hip_runtime.h>
#include <hip/hip_bf16.h>
#include <stdint.h>

#define SEQ    2048
#define HDIM   64
#define NHEAD  16
#define NBATCH 2
#define HID    1024
#define MAXP   2048

typedef __attribute__((ext_vector_type(8))) short bf16x8;
typedef __attribute__((ext_vector_type(4))) float f32x4;

#define MFMA16(a,b,c) __builtin_amdgcn_mfma_f32_16x16x32_bf16((a),(b),(c),0,0,0)

static __device__ __forceinline__ unsigned short f2bf(float x){
  union { __hip_bfloat16 h; unsigned short u; } c; c.h = __float2bfloat16(x); return c.u;
}
static __device__ __forceinline__ float bf2f(unsigned short u){
  union { __hip_bfloat16 h; unsigned short u; } c; c.u = u; return __bfloat162float(c.h);
}
static __device__ __forceinline__ unsigned cvtpk(float lo, float hi){
  unsigned r;
  asm volatile("v_cvt_pk_bf16_f32 %0, %1, %2" : "=v"(r) : "v"(lo), "v"(hi));
  return r;
}
typedef __attribute__((address_space(1))) const void gv_t;
typedef __attribute__((address_space(3))) void lv_t;
static __device__ __forceinline__ void gload16(const void* g, void* l){
  __builtin_amdgcn_global_load_lds((gv_t*)g, (lv_t*)l, 16, 0, 0);
}

// ---------------- f32 -> bf16 convert ----------------
__global__ void cvt_kernel(const float* __restrict__ src, unsigned short* __restrict__ dst, int n4){
  int i = blockIdx.x*blockDim.x + threadIdx.x;
  int stride = gridDim.x*blockDim.x;
  for (int idx = i; idx < n4; idx += stride){
    float4 v = reinterpret_cast<const float4*>(src)[idx];
    ushort4 o;
    o.x = f2bf(v.x); o.y = f2bf(v.y); o.z = f2bf(v.z); o.w = f2bf(v.w);
    reinterpret_cast<ushort4*>(dst)[idx] = o;
  }
}

// ---------------- QKV projection GEMM (unchanged, passing) ----------------
__global__ __launch_bounds__(256,2) void qkv_gemm(
    const unsigned short* __restrict__ X,
    const unsigned short* __restrict__ Wq_, const unsigned short* __restrict__ Wk_,
    const unsigned short* __restrict__ Wv_,
    const float* __restrict__ bq_, const float* __restrict__ bk_, const float* __restrict__ bv_,
    unsigned short* __restrict__ Qb, unsigned short* __restrict__ Kb, unsigned short* __restrict__ Vb)
{
  __shared__ __align__(16) unsigned short Al[128*72];
  __shared__ __align__(16) unsigned short Bl[128*72];
  const int tid = threadIdx.x;
  const int ln = tid & 63, wv = tid >> 6;
  const int l15 = ln & 15, g = ln >> 4;
  const int wr = wv >> 1, wc = wv & 1;

  const int bn = blockIdx.x, bm = blockIdx.y, mat = blockIdx.z;
  const unsigned short* W = (mat==0) ? Wq_ : ((mat==1) ? Wk_ : Wv_);
  const float* bias = (mat==0) ? bq_ : ((mat==1) ? bk_ : bv_);
  unsigned short* Out = (mat==0) ? Qb : ((mat==1) ? Kb : Vb);

  const int m0 = bm*128, n0 = bn*128;

  f32x4 acc[4][4];
  #pragma unroll
  for (int i=0;i<4;++i)
    #pragma unroll
    for (int j=0;j<4;++j) acc[i][j] = (f32x4){0.f,0.f,0.f,0.f};

  for (int kk = 0; kk < HID; kk += 64){
    #pragma unroll
    for (int p=0;p<4;++p){
      int lin = tid + 256*p;
      int row = lin >> 3, ch = lin & 7;
      *reinterpret_cast<bf16x8*>(&Al[row*72 + ch*8]) =
        *reinterpret_cast<const bf16x8*>(&X[(size_t)(m0+row)*HID + kk + ch*8]);
      *reinterpret_cast<bf16x8*>(&Bl[row*72 + ch*8]) =
        *reinterpret_cast<const bf16x8*>(&W[(size_t)(n0+row)*HID + kk + ch*8]);
    }
    __syncthreads();
    bf16x8 a0[4], a1[4], b0[4], b1[4];
    #pragma unroll
    for (int mi=0;mi<4;++mi){
      const unsigned short* p = &Al[(64*wr + 16*mi + l15)*72 + g*8];
      a0[mi] = *reinterpret_cast<const bf16x8*>(p);
      a1[mi] = *reinterpret_cast<const bf16x8*>(p + 32);
    }
    #pragma unroll
    for (int ni=0;ni<4;++ni){
      const unsigned short* p = &Bl[(64*wc + 16*ni + l15)*72 + g*8];
      b0[ni] = *reinterpret_cast<const bf16x8*>(p);
      b1[ni] = *reinterpret_cast<const bf16x8*>(p + 32);
    }
    #pragma unroll
    for (int mi=0;mi<4;++mi)
      #pragma unroll
      for (int ni=0;ni<4;++ni){
        acc[mi][ni] = MFMA16(a0[mi], b0[ni], acc[mi][ni]);
        acc[mi][ni] = MFMA16(a1[mi], b1[ni], acc[mi][ni]);
      }
    __syncthreads();
  }
  #pragma unroll
  for (int mi=0;mi<4;++mi)
    #pragma unroll
    for (int ni=0;ni<4;++ni)
      #pragma unroll
      for (int r=0;r<4;++r){
        int m = m0 + 64*wr + 16*mi + 4*g + r;
        int n = n0 + 64*wc + 16*ni + l15;
        float v = acc[mi][ni][r] + bias[n];
        int b = m >> 11, s = m & 2047;
        int h = n >> 6, d = n & 63;
        Out[(((size_t)(b*NHEAD + h))*SEQ + s)*HDIM + d] = f2bf(v);
      }
}

// ---------------- V transpose: [B,H,S,D] -> [B,H,D,S] ----------------
__global__ void vtrans(const unsigned short* __restrict__ Vb, unsigned short* __restrict__ VTb){
  __shared__ __align__(16) unsigned short Vl[64*72];
  const int tid = threadIdx.x;
  const int blk = blockIdx.x;
  const int st = blk & 31, bh = blk >> 5;
  const int s0 = st*64;
  const unsigned short* src = Vb + (size_t)bh*SEQ*HDIM;
  unsigned short* dst = VTb + (size_t)bh*HDIM*SEQ;
  #pragma unroll
  for (int p=0;p<2;++p){
    int lin = tid + 256*p;
    int row = lin >> 3, ch = lin & 7;
    *reinterpret_cast<bf16x8*>(&Vl[row*72 + ch*8]) =
      *reinterpret_cast<const bf16x8*>(&src[(size_t)(s0+row)*HDIM + ch*8]);
  }
  __syncthreads();
  #pragma unroll
  for (int p=0;p<2;++p){
    int lin = tid + 256*p;
    int drow = lin >> 3, sch = lin & 7;
    bf16x8 v;
    #pragma unroll
    for (int j=0;j<8;++j) v[j] = (short)Vl[(sch*8+j)*72 + drow];
    *reinterpret_cast<bf16x8*>(&dst[(size_t)drow*SEQ + s0 + sch*8]) = v;
  }
}

// ---------------- fused attention, swapped (q-per-lane) layout ----------------
// S^T[k][q] = mfma(K_frag, Q_frag): lane l15 owns q-row q0+16wv+l15.
// G1k[qloc][k] (per-wave, bf16), G2k[qhat][k] (shared, bf16): diagonal folded
// at producer (conditional scalar stores), consumer reads aligned b64.
// K/V/E staged via global_load_lds w/ XOR-swizzled source chunks.
__global__ __launch_bounds__(256,3) void attn_kernel(
    const unsigned short* __restrict__ Qb,
    const unsigned short* __restrict__ Kb,
    const unsigned short* __restrict__ VTb,
    const unsigned short* __restrict__ Eb,
    float* __restrict__ out)
{
  __shared__ __align__(16) unsigned short E_l[128*64];   // 16 KB, swizzled 128B rows
  __shared__ __align__(16) unsigned short K_l[64*64];    // 8 KB
  __shared__ __align__(16) unsigned short V_l[64*64];    // 8 KB  (VT tile [d][k])
  __shared__ __align__(16) unsigned short G2k[64*72];    // 9 KB  [qhat][k]
  __shared__ __align__(16) unsigned char  G1P[4][2304];  // 9 KB  per-wave: G1k[16][72] bf16  U  Pw[16][36] f32

  const int tid = threadIdx.x;
  const int ln = tid & 63, wv = tid >> 6;
  const int l15 = ln & 15, g = ln >> 4;
  const int rsub = ln >> 3, csub = ln & 7;
  const int swch = csub ^ rsub;               // swizzled source chunk for staging
  const int x7 = l15 & 7;
  const int c0 = (g ^ x7) * 8;                // swizzled read offset (elems), d-half 0
  const int c1 = c0 ^ 32;                     // d-half 1

  // XCD-aware swizzle (1024 % 8 == 0 -> simple bijective form)
  const int bid = blockIdx.x;
  const int swz = (bid & 7)*128 + (bid >> 3);
  const int qt = swz & 31, bh = swz >> 5;
  const int q0 = qt*64;

  const unsigned short* Qg = Qb + (size_t)bh*SEQ*HDIM;
  const unsigned short* Kg = Kb + (size_t)bh*SEQ*HDIM;
  const unsigned short* Vg = VTb + (size_t)bh*HDIM*SEQ;

  // Q fragment (B-operand): lane l15 = q-local row
  bf16x8 qa0, qa1;
  {
    const unsigned short* p = &Qg[(size_t)(q0 + 16*wv + l15)*HDIM + 8*g];
    qa0 = *reinterpret_cast<const bf16x8*>(p);
    qa1 = *reinterpret_cast<const bf16x8*>(p + 32);
  }

  f32x4 oacc[4];
  #pragma unroll
  for (int i=0;i<4;++i) oacc[i] = (f32x4){0.f,0.f,0.f,0.f};
  float mrow = -1e30f, lrow = 0.f;

  unsigned short* g1w = (unsigned short*)G1P[wv];
  unsigned*       pww = (unsigned*)G1P[wv];

  // stage issue for one tile (global_load_lds, 0 VGPR, swizzled source)
  auto stage = [&](int k0){
    const int idx_min = 1984 + q0 - k0;
    #pragma unroll
    for (int p=0;p<2;++p){
      int rb = 32*p + 8*wv;
      gload16(&Kg[(size_t)(k0 + rb + rsub)*HDIM + swch*8], (char*)K_l + rb*128);
      gload16(&Vg[(size_t)(rb + rsub)*SEQ + k0 + swch*8], (char*)V_l + rb*128);
    }
    #pragma unroll
    for (int p=0;p<4;++p){
      int rb = 32*p + 8*wv;
      int er = idx_min + rb + rsub;
      if (er > 4094) er = 4094;               // row 127 unused; keep in-bounds
      gload16(&Eb[(size_t)er*HDIM + swch*8], (char*)E_l + rb*128);
    }
  };

  stage(0);   // prologue

  for (int kt = 0; kt < SEQ/64; ++kt){
    const int k0 = kt*64;
    __syncthreads();   // A: drains gloads -> K/V/E ready

    // V fragments -> registers (frees V_l at barrier B)
    bf16x8 vb0[4], vb1[4];
    #pragma unroll
    for (int ctd=0; ctd<4; ++ctd){
      int R = 16*ctd + l15;
      vb0[ctd] = *reinterpret_cast<const bf16x8*>(&V_l[R*64 + c0]);
      vb1[ctd] = *reinterpret_cast<const bf16x8*>(&V_l[R*64 + c1]);
    }

    __builtin_amdgcn_s_setprio(1);
    // ---- G2: wave owns k-band [16wv,16wv+16); D[k][t_rel] -> diag store [qh][k] ----
    {
      int R = 16*wv + l15;
      bf16x8 ka0 = *reinterpret_cast<const bf16x8*>(&K_l[R*64 + c0]);
      bf16x8 ka1 = *reinterpret_cast<const bf16x8*>(&K_l[R*64 + c1]);
      #pragma unroll
      for (int j=0;j<5;++j){
        int Re = 16*(3 - wv + j) + l15;
        bf16x8 eb0 = *reinterpret_cast<const bf16x8*>(&E_l[Re*64 + c0]);
        bf16x8 eb1 = *reinterpret_cast<const bf16x8*>(&E_l[Re*64 + c1]);
        f32x4 a = (f32x4){0.f,0.f,0.f,0.f};
        a = MFMA16(ka0, eb0, a);
        a = MFMA16(ka1, eb1, a);
        #pragma unroll
        for (int r=0;r<4;++r){
          int qh = 16*j + l15 + 4*g + r - 15;
          if ((unsigned)qh < 64u)
            G2k[qh*72 + 16*wv + 4*g + r] = f2bf(a[r]);
        }
      }
    }
    // ---- S1 = K·Q^T (S^T layout) ----
    f32x4 sacc[4];
    #pragma unroll
    for (int ct=0; ct<4; ++ct){
      int R = 16*ct + l15;
      bf16x8 kb0 = *reinterpret_cast<const bf16x8*>(&K_l[R*64 + c0]);
      bf16x8 kb1 = *reinterpret_cast<const bf16x8*>(&K_l[R*64 + c1]);
      f32x4 a = (f32x4){0.f,0.f,0.f,0.f};
      a = MFMA16(kb0, qa0, a);
      a = MFMA16(kb1, qa1, a);
      sacc[ct] = a;
    }
    // ---- G1: D[qloc][t'] -> diag store [qloc][k] (wave-private) ----
    #pragma unroll
    for (int c=0;c<5;++c){
      int Re = 16*wv + 16*c + l15;
      bf16x8 eb0 = *reinterpret_cast<const bf16x8*>(&E_l[Re*64 + c0]);
      bf16x8 eb1 = *reinterpret_cast<const bf16x8*>(&E_l[Re*64 + c1]);
      f32x4 a = (f32x4){0.f,0.f,0.f,0.f};
      a = MFMA16(qa0, eb0, a);
      a = MFMA16(qa1, eb1, a);
      #pragma unroll
      for (int r=0;r<4;++r){
        int k = (4*g + r) + 63 - (16*c + l15);
        if ((unsigned)k < 64u)
          g1w[(4*g + r)*72 + k] = f2bf(a[r]);
      }
    }
    __builtin_amdgcn_s_setprio(0);
    __syncthreads();   // B: G2k visible; all K/V/E reads complete

    if (kt < SEQ/64 - 1) stage(k0 + 64);   // overwrite K/V/E; latency hides under softmax+PV

    // ---- gather (aligned b64) + merge ----
    float sc[4][4];
    #pragma unroll
    for (int ct=0; ct<4; ++ct){
      ushort4 u1 = *reinterpret_cast<const ushort4*>(&g1w[l15*72 + 16*ct + 4*g]);
      ushort4 u2 = *reinterpret_cast<const ushort4*>(&G2k[(16*wv + l15)*72 + 16*ct + 4*g]);
      sc[ct][0] = sacc[ct][0]*0.125f + bf2f(u1.x) + bf2f(u2.x);
      sc[ct][1] = sacc[ct][1]*0.125f + bf2f(u1.y) + bf2f(u2.y);
      sc[ct][2] = sacc[ct][2]*0.125f + bf2f(u1.z) + bf2f(u2.z);
      sc[ct][3] = sacc[ct][3]*0.125f + bf2f(u1.w) + bf2f(u2.w);
    }

    // ---- online softmax: per-lane row, 4 shuffles total ----
    float mx = sc[0][0];
    #pragma unroll
    for (int ct=0;ct<4;++ct)
      #pragma unroll
      for (int r=0;r<4;++r) mx = fmaxf(mx, sc[ct][r]);
    mx = fmaxf(mx, __shfl_xor(mx, 16, 64));
    mx = fmaxf(mx, __shfl_xor(mx, 32, 64));
    float mn = fmaxf(mx, mrow);
    float corr = __expf(mrow - mn);
    float s = 0.f;
    #pragma unroll
    for (int ct=0;ct<4;++ct)
      #pragma unroll
      for (int r=0;r<4;++r){ float pv = __expf(sc[ct][r] - mn); sc[ct][r] = pv; s += pv; }
    s += __shfl_xor(s, 16, 64);
    s += __shfl_xor(s, 32, 64);
    lrow = lrow*corr + s;
    mrow = mn;
    #pragma unroll
    for (int ctd=0;ctd<4;++ctd)
      #pragma unroll
      for (int r=0;r<4;++r) oacc[ctd][r] *= corr;

    // ---- P repack: cvt_pk + wave-private packed store (aliases G1 slab) ----
    #pragma unroll
    for (int ct=0;ct<4;++ct){
      unsigned w0 = cvtpk(sc[ct][0], sc[ct][1]);
      unsigned w1 = cvtpk(sc[ct][2], sc[ct][3]);
      pww[l15*36 + 8*ct + 2*g    ] = w0;
      pww[l15*36 + 8*ct + 2*g + 1] = w1;
    }
    asm volatile("" ::: "memory");   // order packed stores vs typed reads below
    bf16x8 pb0 = *reinterpret_cast<const bf16x8*>(&pww[l15*36 + 4*g]);
    bf16x8 pb1 = *reinterpret_cast<const bf16x8*>(&pww[l15*36 + 16 + 4*g]);

    // ---- PV: O^T += V^T · P^T ----
    __builtin_amdgcn_s_setprio(1);
    #pragma unroll
    for (int ctd=0; ctd<4; ++ctd){
      oacc[ctd] = MFMA16(vb0[ctd], pb0, oacc[ctd]);
      oacc[ctd] = MFMA16(vb1[ctd], pb1, oacc[ctd]);
    }
    __builtin_amdgcn_s_setprio(0);
  }

  // ---- output: O^T fragment -> scalar f32 stores (once per block) ----
  const int b = bh >> 4, h = bh & 15;
  const float inv = 1.0f / lrow;
  const int q = q0 + 16*wv + l15;
  #pragma unroll
  for (int ctd=0; ctd<4; ++ctd)
    #pragma unroll
    for (int r=0;r<4;++r){
      int d = 16*ctd + 4*g + r;
      out[((size_t)(b*SEQ + q))*HID + h*HDIM + d] = oacc[ctd][r] * inv;
    }
}

// ---------------- launch ----------------
extern "C" void kernel_launch(void* const* d_in, const int* in_sizes, int n_in,
                              void* d_out, int out_size, void* d_ws, size_t ws_size,
                              hipStream_t stream){
  const float* hs = (const float*)d_in[0];
  const float* Wq = (const float*)d_in[1];
  const float* bq = (const float*)d_in[2];
  const float* Wk = (const float*)d_in[3];
  const float* bk = (const float*)d_in[4];
  const float* Wv = (const float*)d_in[5];
  const float* bv = (const float*)d_in[6];
  const float* de = (const float*)d_in[7];
  float* out = (float*)d_out;

  char* ws = (char*)d_ws;
  unsigned short* Xb  = (unsigned short*)(ws);                       // 8,388,608 B
  unsigned short* Wqb = (unsigned short*)(ws + 8388608);             // 2 MB
  unsigned short* Wkb = (unsigned short*)(ws + 8388608 + 2097152);
  unsigned short* Wvb = (unsigned short*)(ws + 8388608 + 2*2097152);
  unsigned short* Eb  = (unsigned short*)(ws + 14680064);            // 524,160 B
  unsigned short* Qb  = (unsigned short*)(ws + 15204352);
  unsigned short* Kb  = (unsigned short*)(ws + 23592960);
  unsigned short* Vb  = (unsigned short*)(ws + 31981568);
  unsigned short* VTb = (unsigned short*)(ws + 40370176);            // end 48,758,784

  cvt_kernel<<<1024,256,0,stream>>>(hs, Xb, 4194304/4);
  cvt_kernel<<<512,256,0,stream>>>(Wq, Wqb, 1048576/4);
  cvt_kernel<<<512,256,0,stream>>>(Wk, Wkb, 1048576/4);
  cvt_kernel<<<256,256,0,stream>>>(Wv, Wvb, 1048576/4);
  cvt_kernel<<<256,256,0,stream>>>(de, Eb, 262080/4);

  dim3 gg(8,32,3);
  qkv_gemm<<<gg,256,0,stream>>>(Xb, Wqb, Wkb, Wvb, bq, bk, bv, Qb, Kb, Vb);
  vtrans<<<1024,256,0,stream>>>(Vb, VTb);
  attn_kernel<<<1024,256,0,stream>>>(Qb, Kb, VTb, Eb, out);
}